// Round 1
// baseline (2068.403 us; speedup 1.0000x reference)
//
#include <hip/hip_runtime.h>
#include <hip/hip_bf16.h>
#include <stdint.h>

#define DF   256
#define NBAS 30
#define RREL 64
#define NLAY 3
#define K1   (NBAS*DF)   // 7680
#define EPSBN 1e-5f

typedef short bf16x8 __attribute__((ext_vector_type(8)));
typedef float f32x4  __attribute__((ext_vector_type(4)));

__device__ __forceinline__ ushort f2bf(float f){
  union { float f; uint32_t u; } v; v.f = f;
  uint32_t r = (v.u + 0x7FFFu + ((v.u >> 16) & 1u)) >> 16;
  return (ushort)r;
}

// ---------------- counting sort by dst ----------------
__global__ void k_hist(const int* __restrict__ dst, int* __restrict__ counts, int E){
  int i = blockIdx.x*blockDim.x + threadIdx.x;
  if (i < E) atomicAdd(&counts[dst[i]], 1);
}

__global__ void k_scan(const int* __restrict__ counts, int* __restrict__ offs, int n){
  __shared__ int tmp[1024];
  __shared__ int carry;
  int t = threadIdx.x;
  if (t == 0) carry = 0;
  __syncthreads();
  for (int s = 0; s < n; s += 1024){
    int i = s + t;
    int v = (i < n) ? counts[i] : 0;
    tmp[t] = v;
    __syncthreads();
    for (int o = 1; o < 1024; o <<= 1){
      int u = (t >= o) ? tmp[t - o] : 0;
      __syncthreads();
      tmp[t] += u;
      __syncthreads();
    }
    int incl = tmp[t];
    int base = carry;
    if (i < n) offs[i] = base + incl - v;
    __syncthreads();
    if (t == 1023) carry = base + incl;
    __syncthreads();
  }
  if (t == 0) offs[n] = carry;
}

__global__ void k_place(const int* __restrict__ dst, const int* __restrict__ offs,
                        int* __restrict__ cursor, int* __restrict__ sorted, int E){
  int i = blockIdx.x*blockDim.x + threadIdx.x;
  if (i < E){
    int d = dst[i];
    int p = offs[d] + atomicAdd(&cursor[d], 1);
    sorted[p] = i;
  }
}

// ---------------- transpose fp32 [K,256] -> bf16 [256,K] ----------------
__global__ void k_transpose_bf16(const float* __restrict__ in, ushort* __restrict__ out, int K){
  __shared__ float tile[32][33];
  int k0 = blockIdx.x*32, n0 = blockIdx.y*32;
  int tx = threadIdx.x & 31, ty = threadIdx.x >> 5;  // 32 x 8
  #pragma unroll
  for (int i = 0; i < 32; i += 8)
    tile[ty+i][tx] = in[(size_t)(k0+ty+i)*DF + n0 + tx];
  __syncthreads();
  #pragma unroll
  for (int i = 0; i < 32; i += 8)
    out[(size_t)(n0+ty+i)*K + k0 + tx] = f2bf(tile[tx][ty+i]);
}

// ---------------- edge aggregation: S[v, b*256+k] (bf16) ----------------
__global__ __launch_bounds__(DF) void k_edge_agg(
    const float* __restrict__ h, const int* __restrict__ sorted,
    const int* __restrict__ offs, const int* __restrict__ src,
    const int* __restrict__ et, const float* __restrict__ nrm,
    const float* __restrict__ comp_l, ushort* __restrict__ S, int v0){
  int vl = blockIdx.x;
  int v  = v0 + vl;
  int t  = threadIdx.x;
  float acc[NBAS];
  #pragma unroll
  for (int b = 0; b < NBAS; ++b) acc[b] = 0.f;
  int beg = offs[v], end = offs[v+1];
  for (int j = beg; j < end; ++j){
    int e = sorted[j];
    int s = src[e];
    int r = __builtin_amdgcn_readfirstlane(et[e]);   // block-uniform -> SGPR
    float w  = nrm[e];
    float hv = h[(size_t)s*DF + t] * w;
    const float* cb = comp_l + r*NBAS;
    #pragma unroll
    for (int b = 0; b < NBAS; ++b) acc[b] = fmaf(cb[b], hv, acc[b]);
  }
  ushort* Sr = S + (size_t)vl*K1 + t;
  #pragma unroll
  for (int b = 0; b < NBAS; ++b) Sr[b*DF] = f2bf(acc[b]);
}

// ---------------- bf16 GEMM: C[i,j] = sum_k A[i,k]*Bt[j,k] + bias[j] ----------------
// A: [rows,K] bf16 row-major (rows clamped to a_valid), Bt: [256,K] bf16 row-major.
// 128x128 tile, BK=64, 256 threads (4 waves, 2x2), 16x16x32 MFMA.
template<bool OB>
__global__ __launch_bounds__(256) void k_gemm(
    const ushort* __restrict__ A, const ushort* __restrict__ Bt,
    const float* __restrict__ bias, float* __restrict__ Cf, ushort* __restrict__ Cb,
    int K, int a_valid, int c_off){
  __shared__ ushort As[128*64];
  __shared__ ushort Bs[128*64];
  const int tid  = threadIdx.x;
  const int brow = blockIdx.x*128;
  const int bcol = blockIdx.y*128;
  const int lane = tid & 63, wid = tid >> 6;
  const int wr = (wid >> 1)*64, wc = (wid & 1)*64;
  const int l15 = lane & 15, lhi = lane >> 4;

  const f32x4 z = {0.f, 0.f, 0.f, 0.f};
  f32x4 acc[4][4];
  #pragma unroll
  for (int m = 0; m < 4; ++m)
    #pragma unroll
    for (int n = 0; n < 4; ++n) acc[m][n] = z;

  const int ktiles = K >> 6;
  bf16x8 va[4], vb[4];
  auto LOADG = [&](int kt){
    const int kbase = kt*64;
    #pragma unroll
    for (int i = 0; i < 4; ++i){
      int c   = tid + i*256;
      int row = c >> 3, ko = (c & 7)*8;
      int ra  = brow + row; if (ra >= a_valid) ra = a_valid - 1;
      va[i] = *(const bf16x8*)(A  + (size_t)ra*K + kbase + ko);
      vb[i] = *(const bf16x8*)(Bt + (size_t)(bcol + row)*K + kbase + ko);
    }
  };
  LOADG(0);
  for (int kt = 0; kt < ktiles; ++kt){
    __syncthreads();
    #pragma unroll
    for (int i = 0; i < 4; ++i){
      int c = tid + i*256;
      *(bf16x8*)(As + c*8) = va[i];
      *(bf16x8*)(Bs + c*8) = vb[i];
    }
    __syncthreads();
    if (kt + 1 < ktiles) LOADG(kt + 1);
    #pragma unroll
    for (int ks = 0; ks < 2; ++ks){
      const int kb = ks*32 + lhi*8;
      bf16x8 af[4], bfr[4];
      #pragma unroll
      for (int m = 0; m < 4; ++m) af[m]  = *(const bf16x8*)(As + (wr + m*16 + l15)*64 + kb);
      #pragma unroll
      for (int n = 0; n < 4; ++n) bfr[n] = *(const bf16x8*)(Bs + (wc + n*16 + l15)*64 + kb);
      #pragma unroll
      for (int m = 0; m < 4; ++m)
        #pragma unroll
        for (int n = 0; n < 4; ++n)
          acc[m][n] = __builtin_amdgcn_mfma_f32_16x16x32_bf16(af[m], bfr[n], acc[m][n], 0, 0, 0);
    }
  }
  #pragma unroll
  for (int m = 0; m < 4; ++m){
    #pragma unroll
    for (int n = 0; n < 4; ++n){
      int col  = bcol + wc + n*16 + l15;
      float bv = bias[col];
      #pragma unroll
      for (int r = 0; r < 4; ++r){
        int grow = c_off + brow + wr + m*16 + lhi*4 + r;
        float v  = acc[m][n][r] + bv;
        if (OB) Cb[(size_t)grow*DF + col] = f2bf(v);
        else    Cf[(size_t)grow*DF + col] = v;
      }
    }
  }
}

// ---------------- BatchNorm ----------------
__global__ __launch_bounds__(256) void k_bn_stats(const float* __restrict__ y,
    float* __restrict__ msum, float* __restrict__ ssum, int nrows){
  int t  = threadIdx.x;
  int r0 = blockIdx.x*128;
  int r1 = min(r0 + 128, nrows);
  float s = 0.f, s2 = 0.f;
  for (int r = r0; r < r1; ++r){
    float v = y[(size_t)r*DF + t];
    s += v; s2 = fmaf(v, v, s2);
  }
  atomicAdd(&msum[t], s);
  atomicAdd(&ssum[t], s2);
}

__global__ void k_bn_finalize(const float* __restrict__ msum, const float* __restrict__ ssum,
    const float* __restrict__ g, const float* __restrict__ bt,
    float* __restrict__ scale, float* __restrict__ shift, int nrows){
  int t = threadIdx.x;
  float inv = 1.f / (float)nrows;
  float mu  = msum[t]*inv;
  float var = ssum[t]*inv - mu*mu;
  float rs  = rsqrtf(var + EPSBN);
  float sc  = g[t]*rs;
  scale[t] = sc;
  shift[t] = bt[t] - mu*sc;
}

template<bool OB>
__global__ __launch_bounds__(256) void k_bn_apply(const float* __restrict__ y,
    const float* __restrict__ scale, const float* __restrict__ shift,
    float* __restrict__ of, ushort* __restrict__ ob){
  int i   = blockIdx.x*256 + threadIdx.x;
  int col = i & (DF-1);
  float v = fmaxf(0.f, fmaf(y[i], scale[col], shift[col]));
  if (OB) ob[i] = f2bf(v); else of[i] = v;
}

// ---------------- launch ----------------
extern "C" void kernel_launch(void* const* d_in, const int* in_sizes, int n_in,
                              void* d_out, int out_size, void* d_ws, size_t ws_size,
                              hipStream_t stream){
  const float* h0   = (const float*)d_in[0];
  const float* norm = (const float*)d_in[1];
  const float* V    = (const float*)d_in[2];
  const float* comp = (const float*)d_in[3];
  const float* bias = (const float*)d_in[4];
  const float* W1   = (const float*)d_in[5];
  const float* b1   = (const float*)d_in[6];
  const float* g1   = (const float*)d_in[7];
  const float* bt1  = (const float*)d_in[8];
  const float* W2   = (const float*)d_in[9];
  const float* b2   = (const float*)d_in[10];
  const float* g2   = (const float*)d_in[11];
  const float* bt2  = (const float*)d_in[12];
  const int* src    = (const int*)d_in[13];
  const int* dst    = (const int*)d_in[14];
  const int* et     = (const int*)d_in[15];

  const int N  = in_sizes[0] / DF;     // 20000
  const int E  = in_sizes[13];         // 320000
  const int MT = (N + 127) / 128;      // 157
  const int MP = MT * 128;             // 20096
  float* out = (float*)d_out;

  uint8_t* w = (uint8_t*)d_ws;
  size_t o = 0;
  auto carve = [&](size_t bytes)->void*{
    void* p = w + o;
    o = (o + bytes + 511) & ~(size_t)511;
    return p;
  };
  float*  y      = (float*) carve((size_t)MP*DF*4);
  ushort* xb     = (ushort*)carve((size_t)MP*DF*2);
  ushort* Vt     = (ushort*)carve((size_t)DF*K1*2);
  ushort* W1t    = (ushort*)carve((size_t)DF*DF*2);
  ushort* W2t    = (ushort*)carve((size_t)DF*DF*2);
  float*  msum   = (float*) carve(DF*4);
  float*  ssum   = (float*) carve(DF*4);
  float*  scal   = (float*) carve(DF*4);
  float*  shif   = (float*) carve(DF*4);
  int*    counts = (int*)   carve((size_t)N*4);
  int*    cursor = (int*)   carve((size_t)N*4);
  int*    offs   = (int*)   carve((size_t)(N+1)*4);
  int*    sorted = (int*)   carve((size_t)E*4);
  ushort* S      = (ushort*)(w + o);
  size_t srem = (ws_size > o) ? (ws_size - o) : 0;
  long long crl = (long long)(srem / ((size_t)K1*2)) / 128 * 128;
  int CR = (int)((crl > MP) ? MP : crl);
  if (CR < 128) CR = 128;   // assume ws is at least modestly sized

  // edge sort by dst (layer-invariant)
  hipMemsetAsync(counts, 0, (size_t)N*4, stream);
  hipMemsetAsync(cursor, 0, (size_t)N*4, stream);
  k_hist <<<(E+255)/256, 256, 0, stream>>>(dst, counts, E);
  k_scan <<<1, 1024, 0, stream>>>(counts, offs, N);
  k_place<<<(E+255)/256, 256, 0, stream>>>(dst, offs, cursor, sorted, E);

  // reps[0] = h
  hipMemcpyAsync(out, h0, (size_t)N*DF*4, hipMemcpyDeviceToDevice, stream);

  for (int l = 0; l < NLAY; ++l){
    const float* hl = out + (size_t)l*N*DF;
    k_transpose_bf16<<<dim3(K1/32, DF/32), 256, 0, stream>>>(V  + (size_t)l*K1*DF, Vt,  K1);
    k_transpose_bf16<<<dim3(DF/32, DF/32), 256, 0, stream>>>(W1 + (size_t)l*DF*DF, W1t, DF);
    k_transpose_bf16<<<dim3(DF/32, DF/32), 256, 0, stream>>>(W2 + (size_t)l*DF*DF, W2t, DF);
    const float* comp_l = comp + (size_t)l*RREL*NBAS;

    for (int c0 = 0; c0 < N; c0 += CR){
      int rows = (N - c0 < CR) ? (N - c0) : CR;
      int gm   = (rows + 127) / 128;
      k_edge_agg<<<rows, DF, 0, stream>>>(hl, sorted, offs, src, et, norm, comp_l, S, c0);
      k_gemm<true><<<dim3(gm, 2), 256, 0, stream>>>(S, Vt, bias + (size_t)l*DF,
                                                    nullptr, xb, K1, rows, c0);
    }
    // y1 = x @ W1 + b1
    k_gemm<false><<<dim3(MT, 2), 256, 0, stream>>>(xb, W1t, b1 + (size_t)l*DF,
                                                   y, nullptr, DF, N, 0);
    hipMemsetAsync(msum, 0, DF*4, stream);
    hipMemsetAsync(ssum, 0, DF*4, stream);
    k_bn_stats   <<<MT, 256, 0, stream>>>(y, msum, ssum, N);
    k_bn_finalize<<<1, DF, 0, stream>>>(msum, ssum, g1 + (size_t)l*DF, bt1 + (size_t)l*DF, scal, shif, N);
    k_bn_apply<true><<<(N*DF)/256, 256, 0, stream>>>(y, scal, shif, nullptr, xb);
    // y2 = x1 @ W2 + b2
    k_gemm<false><<<dim3(MT, 2), 256, 0, stream>>>(xb, W2t, b2 + (size_t)l*DF,
                                                   y, nullptr, DF, N, 0);
    hipMemsetAsync(msum, 0, DF*4, stream);
    hipMemsetAsync(ssum, 0, DF*4, stream);
    k_bn_stats   <<<MT, 256, 0, stream>>>(y, msum, ssum, N);
    k_bn_finalize<<<1, DF, 0, stream>>>(msum, ssum, g2 + (size_t)l*DF, bt2 + (size_t)l*DF, scal, shif, N);
    k_bn_apply<false><<<(N*DF)/256, 256, 0, stream>>>(y, scal, shif, out + (size_t)(l+1)*N*DF, nullptr);
  }
}

// Round 2
// 1446.122 us; speedup vs baseline: 1.4303x; 1.4303x over previous
//
#include <hip/hip_runtime.h>
#include <hip/hip_bf16.h>
#include <stdint.h>

#define DF   256
#define NBAS 30
#define RREL 64
#define NLAY 3
#define K1   (NBAS*DF)   // 7680
#define EPSBN 1e-5f
#define SPLITK 4

typedef short  bf16x8 __attribute__((ext_vector_type(8)));
typedef float  f32x4  __attribute__((ext_vector_type(4)));
typedef ushort u16x4  __attribute__((ext_vector_type(4)));

__device__ __forceinline__ ushort f2bf(float f){
  union { float f; uint32_t u; } v; v.f = f;
  uint32_t r = (v.u + 0x7FFFu + ((v.u >> 16) & 1u)) >> 16;
  return (ushort)r;
}

// ---------------- counting sort by dst ----------------
__global__ void k_hist(const int* __restrict__ dst, int* __restrict__ counts, int E){
  int i = blockIdx.x*blockDim.x + threadIdx.x;
  if (i < E) atomicAdd(&counts[dst[i]], 1);
}

__global__ void k_scan(const int* __restrict__ counts, int* __restrict__ offs, int n){
  __shared__ int tmp[1024];
  __shared__ int carry;
  int t = threadIdx.x;
  if (t == 0) carry = 0;
  __syncthreads();
  for (int s = 0; s < n; s += 1024){
    int i = s + t;
    int v = (i < n) ? counts[i] : 0;
    tmp[t] = v;
    __syncthreads();
    for (int o = 1; o < 1024; o <<= 1){
      int u = (t >= o) ? tmp[t - o] : 0;
      __syncthreads();
      tmp[t] += u;
      __syncthreads();
    }
    int incl = tmp[t];
    int base = carry;
    if (i < n) offs[i] = base + incl - v;
    __syncthreads();
    if (t == 1023) carry = base + incl;
    __syncthreads();
  }
  if (t == 0) offs[n] = carry;
}

__global__ void k_place(const int* __restrict__ dst, const int* __restrict__ offs,
                        int* __restrict__ cursor, int* __restrict__ sorted, int E){
  int i = blockIdx.x*blockDim.x + threadIdx.x;
  if (i < E){
    int d = dst[i];
    int p = offs[d] + atomicAdd(&cursor[d], 1);
    sorted[p] = i;
  }
}

// ---------------- transpose fp32 [K,256] -> bf16 [256,K], layered via z ----------------
__global__ void k_transpose_bf16(const float* __restrict__ in, ushort* __restrict__ out, int K){
  const float* inz  = in  + (size_t)blockIdx.z*K*DF;
  ushort*      outz = out + (size_t)blockIdx.z*DF*K;
  __shared__ float tile[32][33];
  int k0 = blockIdx.x*32, n0 = blockIdx.y*32;
  int tx = threadIdx.x & 31, ty = threadIdx.x >> 5;  // 32 x 8
  #pragma unroll
  for (int i = 0; i < 32; i += 8)
    tile[ty+i][tx] = inz[(size_t)(k0+ty+i)*DF + n0 + tx];
  __syncthreads();
  #pragma unroll
  for (int i = 0; i < 32; i += 8)
    outz[(size_t)(n0+ty+i)*K + k0 + tx] = f2bf(tile[tx][ty+i]);
}

// ---------------- edge aggregation: S[vl, b*256+t] (bf16, chunk-local) ----------------
__global__ __launch_bounds__(DF) void k_edge_agg(
    const float* __restrict__ h, const int* __restrict__ sorted,
    const int* __restrict__ offs, const int* __restrict__ src,
    const int* __restrict__ et, const float* __restrict__ nrm,
    const float* __restrict__ comp_l, ushort* __restrict__ S, int v0){
  int vl = blockIdx.x;
  int v  = v0 + vl;
  int t  = threadIdx.x;
  float acc[NBAS];
  #pragma unroll
  for (int b = 0; b < NBAS; ++b) acc[b] = 0.f;
  int beg = offs[v], end = offs[v+1];
  for (int j = beg; j < end; ++j){
    int e = sorted[j];
    int s = src[e];
    int r = __builtin_amdgcn_readfirstlane(et[e]);   // block-uniform -> SGPR
    float w  = nrm[e];
    float hv = h[(size_t)s*DF + t] * w;
    const float* cb = comp_l + r*NBAS;
    #pragma unroll
    for (int b = 0; b < NBAS; ++b) acc[b] = fmaf(cb[b], hv, acc[b]);
  }
  ushort* Sr = S + (size_t)vl*K1 + t;
  #pragma unroll
  for (int b = 0; b < NBAS; ++b) Sr[b*DF] = f2bf(acc[b]);
}

// ---------------- bf16 GEMM core ----------------
// MODE 0: split-K partial — out = P + blockIdx.z*zstride, raw fp32 accs, K-range by z.
// MODE 1: MLP GEMM — out = y (+bias), fused BN column stats via shfl+atomicAdd.
template<int MODE>
__global__ __launch_bounds__(256) void k_gemm(
    const ushort* __restrict__ A, const ushort* __restrict__ Bt,
    const float* __restrict__ bias, float* __restrict__ outp,
    float* __restrict__ msum, float* __restrict__ ssum,
    int K, int kiters, int a_valid, int c_off, size_t zstride){
  __shared__ ushort As[128*64];
  __shared__ ushort Bs[128*64];
  const int tid  = threadIdx.x;
  const int brow = blockIdx.x*128;
  const int bcol = blockIdx.y*128;
  const int lane = tid & 63, wid = tid >> 6;
  const int wr = (wid >> 1)*64, wc = (wid & 1)*64;
  const int l15 = lane & 15, lhi = lane >> 4;
  const int k0 = (MODE == 0) ? (int)blockIdx.z*kiters*64 : 0;
  float* out = (MODE == 0) ? (outp + (size_t)blockIdx.z*zstride) : outp;

  const f32x4 z = {0.f, 0.f, 0.f, 0.f};
  f32x4 acc[4][4];
  #pragma unroll
  for (int m = 0; m < 4; ++m)
    #pragma unroll
    for (int n = 0; n < 4; ++n) acc[m][n] = z;

  bf16x8 va[4], vb[4];
  auto LOADG = [&](int kt){
    const int kbase = k0 + kt*64;
    #pragma unroll
    for (int i = 0; i < 4; ++i){
      int c   = tid + i*256;
      int row = c >> 3, ko = (c & 7)*8;
      int ra  = brow + row; if (ra >= a_valid) ra = a_valid - 1;
      va[i] = *(const bf16x8*)(A  + (size_t)ra*K + kbase + ko);
      vb[i] = *(const bf16x8*)(Bt + (size_t)(bcol + row)*K + kbase + ko);
    }
  };
  LOADG(0);
  for (int kt = 0; kt < kiters; ++kt){
    __syncthreads();
    #pragma unroll
    for (int i = 0; i < 4; ++i){
      int c = tid + i*256;
      *(bf16x8*)(As + c*8) = va[i];
      *(bf16x8*)(Bs + c*8) = vb[i];
    }
    __syncthreads();
    if (kt + 1 < kiters) LOADG(kt + 1);
    #pragma unroll
    for (int ks = 0; ks < 2; ++ks){
      const int kb = ks*32 + lhi*8;
      bf16x8 af[4], bfr[4];
      #pragma unroll
      for (int m = 0; m < 4; ++m) af[m]  = *(const bf16x8*)(As + (wr + m*16 + l15)*64 + kb);
      #pragma unroll
      for (int n = 0; n < 4; ++n) bfr[n] = *(const bf16x8*)(Bs + (wc + n*16 + l15)*64 + kb);
      #pragma unroll
      for (int m = 0; m < 4; ++m)
        #pragma unroll
        for (int n = 0; n < 4; ++n)
          acc[m][n] = __builtin_amdgcn_mfma_f32_16x16x32_bf16(af[m], bfr[n], acc[m][n], 0, 0, 0);
    }
  }

  #pragma unroll
  for (int n = 0; n < 4; ++n){
    const int col = bcol + wc + n*16 + l15;
    const float bv = (MODE == 1) ? bias[col] : 0.f;
    float s = 0.f, s2 = 0.f;
    #pragma unroll
    for (int m = 0; m < 4; ++m){
      #pragma unroll
      for (int r = 0; r < 4; ++r){
        int grow = c_off + brow + wr + m*16 + lhi*4 + r;
        float v  = acc[m][n][r] + bv;
        out[(size_t)grow*DF + col] = v;
        if (MODE == 1 && grow < a_valid){ s += v; s2 = fmaf(v, v, s2); }
      }
    }
    if (MODE == 1){
      s  += __shfl_xor(s, 16);  s  += __shfl_xor(s, 32);
      s2 += __shfl_xor(s2, 16); s2 += __shfl_xor(s2, 32);
      if (lhi == 0){ atomicAdd(&msum[col], s); atomicAdd(&ssum[col], s2); }
    }
  }
}

// ---------------- split-K reduce + bias -> bf16 ----------------
__global__ __launch_bounds__(256) void k_reduce4(const float* __restrict__ P, size_t zst,
    const float* __restrict__ bias, ushort* __restrict__ xb){
  size_t i = ((size_t)blockIdx.x*blockDim.x + threadIdx.x)*4;
  int col = (int)(i & (DF-1));
  f32x4 a = *(const f32x4*)(P + i);
  f32x4 b = *(const f32x4*)(P + zst + i);
  f32x4 c = *(const f32x4*)(P + 2*zst + i);
  f32x4 d = *(const f32x4*)(P + 3*zst + i);
  f32x4 bv = *(const f32x4*)(bias + col);
  u16x4 o;
  #pragma unroll
  for (int j = 0; j < 4; ++j) o[j] = f2bf(a[j] + b[j] + c[j] + d[j] + bv[j]);
  *(u16x4*)(xb + i) = o;
}

// ---------------- BatchNorm finalize (zeroes accumulators for next use) ----------------
__global__ void k_bn_finalize(float* __restrict__ msum, float* __restrict__ ssum,
    const float* __restrict__ g, const float* __restrict__ bt,
    float* __restrict__ scale, float* __restrict__ shift, int nrows){
  int t = threadIdx.x;
  float inv = 1.f / (float)nrows;
  float mu  = msum[t]*inv;
  float var = ssum[t]*inv - mu*mu;
  float rs  = rsqrtf(var + EPSBN);
  float sc  = g[t]*rs;
  scale[t] = sc;
  shift[t] = bt[t] - mu*sc;
  msum[t] = 0.f; ssum[t] = 0.f;
}

template<bool OB>
__global__ __launch_bounds__(256) void k_bn_apply(const float* __restrict__ y,
    const float* __restrict__ scale, const float* __restrict__ shift,
    float* __restrict__ of, ushort* __restrict__ ob){
  size_t i = ((size_t)blockIdx.x*blockDim.x + threadIdx.x)*4;
  int col = (int)(i & (DF-1));
  f32x4 v  = *(const f32x4*)(y + i);
  f32x4 sc = *(const f32x4*)(scale + col);
  f32x4 sh = *(const f32x4*)(shift + col);
  if (OB){
    u16x4 o;
    #pragma unroll
    for (int j = 0; j < 4; ++j) o[j] = f2bf(fmaxf(0.f, fmaf(v[j], sc[j], sh[j])));
    *(u16x4*)(ob + i) = o;
  } else {
    f32x4 o;
    #pragma unroll
    for (int j = 0; j < 4; ++j) o[j] = fmaxf(0.f, fmaf(v[j], sc[j], sh[j]));
    *(f32x4*)(of + i) = o;
  }
}

// ---------------- launch ----------------
extern "C" void kernel_launch(void* const* d_in, const int* in_sizes, int n_in,
                              void* d_out, int out_size, void* d_ws, size_t ws_size,
                              hipStream_t stream){
  const float* h0   = (const float*)d_in[0];
  const float* norm = (const float*)d_in[1];
  const float* V    = (const float*)d_in[2];
  const float* comp = (const float*)d_in[3];
  const float* bias = (const float*)d_in[4];
  const float* W1   = (const float*)d_in[5];
  const float* b1   = (const float*)d_in[6];
  const float* g1   = (const float*)d_in[7];
  const float* bt1  = (const float*)d_in[8];
  const float* W2   = (const float*)d_in[9];
  const float* b2   = (const float*)d_in[10];
  const float* g2   = (const float*)d_in[11];
  const float* bt2  = (const float*)d_in[12];
  const int* src    = (const int*)d_in[13];
  const int* dst    = (const int*)d_in[14];
  const int* et     = (const int*)d_in[15];

  const int N  = in_sizes[0] / DF;     // 20000
  const int E  = in_sizes[13];         // 320000
  const int MT = (N + 127) / 128;      // 157
  const int MP = MT * 128;             // 20096
  const size_t MPDF = (size_t)MP * DF;
  float* out = (float*)d_out;

  uint8_t* w = (uint8_t*)d_ws;
  size_t o = 0;
  auto carve = [&](size_t bytes)->void*{
    void* p = w + o;
    o = (o + bytes + 511) & ~(size_t)511;
    return p;
  };
  float*  P      = (float*) carve(MPDF*4*SPLITK);        // P0..P3 contiguous; P0 doubles as y
  float*  y      = P;
  ushort* xb     = (ushort*)carve(MPDF*2);
  ushort* Vt     = (ushort*)carve((size_t)NLAY*DF*K1*2);
  ushort* W1t    = (ushort*)carve((size_t)NLAY*DF*DF*2);
  ushort* W2t    = (ushort*)carve((size_t)NLAY*DF*DF*2);
  float*  msum   = (float*) carve(DF*4);
  float*  ssum   = (float*) carve(DF*4);
  float*  scal   = (float*) carve(DF*4);
  float*  shif   = (float*) carve(DF*4);
  int*    counts = (int*)   carve((size_t)N*4);
  int*    cursor = (int*)   carve((size_t)N*4);
  int*    offs   = (int*)   carve((size_t)(N+1)*4);
  int*    sorted = (int*)   carve((size_t)E*4);
  ushort* S      = (ushort*)(w + o);
  size_t srem = (ws_size > o) ? (ws_size - o) : 0;
  long long crl = ((long long)(srem / ((size_t)K1*2))) & ~127LL;
  long long cap = 8192; // keep S chunk L3-resident (~126 MB)
  int CR = (int)((crl > cap) ? cap : crl);
  if (CR > MP) CR = MP;
  if (CR < 128) CR = 128;

  // one-time zeroing (ws re-poisoned every call)
  hipMemsetAsync(counts, 0, (size_t)N*4, stream);
  hipMemsetAsync(cursor, 0, (size_t)N*4, stream);
  hipMemsetAsync(msum, 0, 2*DF*4, stream);   // msum+ssum contiguous (512B-aligned carves)

  // edge sort by dst (layer-invariant)
  k_hist <<<(E+255)/256, 256, 0, stream>>>(dst, counts, E);
  k_scan <<<1, 1024, 0, stream>>>(counts, offs, N);
  k_place<<<(E+255)/256, 256, 0, stream>>>(dst, offs, cursor, sorted, E);

  // reps[0] = h
  hipMemcpyAsync(out, h0, (size_t)N*DF*4, hipMemcpyDeviceToDevice, stream);

  // all weight transposes upfront
  k_transpose_bf16<<<dim3(K1/32, DF/32, NLAY), 256, 0, stream>>>(V,  Vt,  K1);
  k_transpose_bf16<<<dim3(DF/32, DF/32, NLAY), 256, 0, stream>>>(W1, W1t, DF);
  k_transpose_bf16<<<dim3(DF/32, DF/32, NLAY), 256, 0, stream>>>(W2, W2t, DF);

  const int kspl = K1/64/SPLITK;  // 30
  for (int l = 0; l < NLAY; ++l){
    const float* hl     = out + (size_t)l*N*DF;
    const float* comp_l = comp + (size_t)l*RREL*NBAS;
    const ushort* Vtl   = Vt + (size_t)l*DF*K1;

    for (int c0 = 0; c0 < N; c0 += CR){
      int rows = (N - c0 < CR) ? (N - c0) : CR;
      int gm   = (rows + 127) / 128;
      k_edge_agg<<<rows, DF, 0, stream>>>(hl, sorted, offs, src, et, norm, comp_l, S, c0);
      k_gemm<0><<<dim3(gm, 2, SPLITK), 256, 0, stream>>>(S, Vtl, nullptr, P,
                                                         nullptr, nullptr,
                                                         K1, kspl, rows, c0, MPDF);
    }
    k_reduce4<<<(int)(MPDF/1024), 256, 0, stream>>>(P, MPDF, bias + (size_t)l*DF, xb);

    // y1 = x @ W1 + b1 (+fused BN1 stats)
    k_gemm<1><<<dim3(MT, 2), 256, 0, stream>>>(xb, W1t + (size_t)l*DF*DF, b1 + (size_t)l*DF,
                                               y, msum, ssum, DF, 4, N, 0, 0);
    k_bn_finalize<<<1, DF, 0, stream>>>(msum, ssum, g1 + (size_t)l*DF, bt1 + (size_t)l*DF, scal, shif, N);
    k_bn_apply<true><<<(int)((size_t)N*DF/1024), 256, 0, stream>>>(y, scal, shif, nullptr, xb);

    // y2 = x1 @ W2 + b2 (+fused BN2 stats)
    k_gemm<1><<<dim3(MT, 2), 256, 0, stream>>>(xb, W2t + (size_t)l*DF*DF, b2 + (size_t)l*DF,
                                               y, msum, ssum, DF, 4, N, 0, 0);
    k_bn_finalize<<<1, DF, 0, stream>>>(msum, ssum, g2 + (size_t)l*DF, bt2 + (size_t)l*DF, scal, shif, N);
    k_bn_apply<false><<<(int)((size_t)N*DF/1024), 256, 0, stream>>>(y, scal, shif,
                                               out + (size_t)(l+1)*N*DF, nullptr);
  }
}

// Round 4
// 1279.870 us; speedup vs baseline: 1.6161x; 1.1299x over previous
//
#include <hip/hip_runtime.h>
#include <hip/hip_bf16.h>
#include <stdint.h>

#define DF   256
#define NBAS 30
#define RREL 64
#define NLAY 3
#define K1   (NBAS*DF)   // 7680
#define EPSBN 1e-5f
#define SPLITK 6
#define CRMAX 8192

typedef short  bf16x8 __attribute__((ext_vector_type(8)));
typedef float  f32x4  __attribute__((ext_vector_type(4)));
typedef ushort u16x4  __attribute__((ext_vector_type(4)));

typedef __attribute__((address_space(1))) const unsigned int gu32;
typedef __attribute__((address_space(3))) unsigned int       lu32;

__device__ __forceinline__ void gload16(const void* g, void* l){
  __builtin_amdgcn_global_load_lds((gu32*)g, (lu32*)l, 16, 0, 0);
}

__device__ __forceinline__ ushort f2bf(float f){
  union { float f; uint32_t u; } v; v.f = f;
  uint32_t r = (v.u + 0x7FFFu + ((v.u >> 16) & 1u)) >> 16;
  return (ushort)r;
}

// ---------------- counting sort by dst (+ metadata gather) ----------------
__global__ void k_hist(const int* __restrict__ dst, int* __restrict__ counts, int E){
  int i = blockIdx.x*blockDim.x + threadIdx.x;
  if (i < E) atomicAdd(&counts[dst[i]], 1);
}

__global__ void k_scan(const int* __restrict__ counts, int* __restrict__ offs, int n){
  __shared__ int tmp[1024];
  __shared__ int carry;
  int t = threadIdx.x;
  if (t == 0) carry = 0;
  __syncthreads();
  for (int s = 0; s < n; s += 1024){
    int i = s + t;
    int v = (i < n) ? counts[i] : 0;
    tmp[t] = v;
    __syncthreads();
    for (int o = 1; o < 1024; o <<= 1){
      int u = (t >= o) ? tmp[t - o] : 0;
      __syncthreads();
      tmp[t] += u;
      __syncthreads();
    }
    int incl = tmp[t];
    int base = carry;
    if (i < n) offs[i] = base + incl - v;
    __syncthreads();
    if (t == 1023) carry = base + incl;
    __syncthreads();
  }
  if (t == 0) offs[n] = carry;
}

__global__ void k_place(const int* __restrict__ dst, const int* __restrict__ offs,
                        int* __restrict__ cursor,
                        const int* __restrict__ src, const int* __restrict__ et,
                        const float* __restrict__ nrm,
                        int* __restrict__ srcs, int* __restrict__ ets,
                        float* __restrict__ nrms, int E){
  int i = blockIdx.x*blockDim.x + threadIdx.x;
  if (i < E){
    int d = dst[i];
    int p = offs[d] + atomicAdd(&cursor[d], 1);
    srcs[p] = src[i];
    ets[p]  = et[i];
    nrms[p] = nrm[i];
  }
}

// ---------------- transpose fp32 [K,256] -> bf16 [256,K], layered via z ----------------
__global__ void k_transpose_bf16(const float* __restrict__ in, ushort* __restrict__ out, int K){
  const float* inz  = in  + (size_t)blockIdx.z*K*DF;
  ushort*      outz = out + (size_t)blockIdx.z*DF*K;
  __shared__ float tile[32][33];
  int k0 = blockIdx.x*32, n0 = blockIdx.y*32;
  int tx = threadIdx.x & 31, ty = threadIdx.x >> 5;  // 32 x 8
  #pragma unroll
  for (int i = 0; i < 32; i += 8)
    tile[ty+i][tx] = inz[(size_t)(k0+ty+i)*DF + n0 + tx];
  __syncthreads();
  #pragma unroll
  for (int i = 0; i < 32; i += 8)
    outz[(size_t)(n0+ty+i)*K + k0 + tx] = f2bf(tile[tx][ty+i]);
}

// ---------------- edge aggregation: S[vl, b*256+t] (bf16, chunk-local) ----------------
__global__ __launch_bounds__(DF) void k_edge_agg(
    const float* __restrict__ h, const int* __restrict__ srcs,
    const int* __restrict__ ets, const float* __restrict__ nrms,
    const int* __restrict__ offs, const float* __restrict__ comp_l,
    ushort* __restrict__ S, int v0){
  const int v = v0 + blockIdx.x;
  const int t = threadIdx.x;
  float acc[NBAS];
  #pragma unroll
  for (int b = 0; b < NBAS; ++b) acc[b] = 0.f;
  const int beg = offs[v], end = offs[v+1];
  int j = beg;
  for (; j + 4 <= end; j += 4){
    int s0 = srcs[j], s1 = srcs[j+1], s2 = srcs[j+2], s3 = srcs[j+3];
    float w0 = nrms[j], w1 = nrms[j+1], w2 = nrms[j+2], w3 = nrms[j+3];
    int r0 = ets[j], r1 = ets[j+1], r2 = ets[j+2], r3 = ets[j+3];
    const float* c0 = comp_l + r0*NBAS;
    const float* c1 = comp_l + r1*NBAS;
    const float* c2 = comp_l + r2*NBAS;
    const float* c3 = comp_l + r3*NBAS;
    float h0 = h[(size_t)s0*DF + t] * w0;
    float h1 = h[(size_t)s1*DF + t] * w1;
    float h2 = h[(size_t)s2*DF + t] * w2;
    float h3 = h[(size_t)s3*DF + t] * w3;
    #pragma unroll
    for (int b = 0; b < NBAS; ++b)
      acc[b] = fmaf(c3[b], h3, fmaf(c2[b], h2, fmaf(c1[b], h1, fmaf(c0[b], h0, acc[b]))));
  }
  for (; j < end; ++j){
    const float* c0 = comp_l + ets[j]*NBAS;
    float h0 = h[(size_t)srcs[j]*DF + t] * nrms[j];
    #pragma unroll
    for (int b = 0; b < NBAS; ++b) acc[b] = fmaf(c0[b], h0, acc[b]);
  }
  ushort* Sr = S + (size_t)blockIdx.x*K1 + t;
  #pragma unroll
  for (int b = 0; b < NBAS; ++b) Sr[b*DF] = f2bf(acc[b]);
}

// ---------------- bf16 GEMM core (global_load_lds staging, m97 structure) ----------------
// MODE 0: split-K partial -> P + z*zst (chunk-local rows, fp32 raw)
// MODE 1: MLP GEMM -> y (+bias), fused BN column stats via shfl+atomicAdd
template<int MODE>
__global__ __launch_bounds__(256) void k_gemm(
    const ushort* __restrict__ A, const ushort* __restrict__ Bt,
    const float* __restrict__ bias, float* __restrict__ outp,
    float* __restrict__ msum, float* __restrict__ ssum,
    int K, int kiters, int a_valid, size_t zst){
  __shared__ __align__(16) ushort As[128*64];
  __shared__ __align__(16) ushort Bs[128*64];
  const int tid  = threadIdx.x;
  const int brow = blockIdx.x*128;
  const int bcol = blockIdx.y*128;
  const int lane = tid & 63, wid = tid >> 6;
  const int wr = (wid >> 1)*64, wc = (wid & 1)*64;
  const int l15 = lane & 15, lhi = lane >> 4;
  const int k0 = (MODE == 0) ? (int)blockIdx.z*kiters*64 : 0;
  float* out = (MODE == 0) ? (outp + (size_t)blockIdx.z*zst) : outp;

  const f32x4 z = {0.f, 0.f, 0.f, 0.f};
  f32x4 acc[4][4];
  #pragma unroll
  for (int m = 0; m < 4; ++m)
    #pragma unroll
    for (int n = 0; n < 4; ++n) acc[m][n] = z;

  for (int kt = 0; kt < kiters; ++kt){
    const int kbase = k0 + kt*64;
    __syncthreads();   // all waves done reading LDS from previous tile
    #pragma unroll
    for (int i = 0; i < 4; ++i){
      int c   = tid + i*256;
      int row = c >> 3, ko = (c & 7)*8;
      int ra  = brow + row; if (ra >= a_valid) ra = a_valid - 1;
      gload16(A  + (size_t)ra*K + kbase + ko,           As + c*8);
      gload16(Bt + (size_t)(bcol + row)*K + kbase + ko, Bs + c*8);
    }
    __syncthreads();   // compiler drains vmcnt(0) here -> LDS tile ready
    #pragma unroll
    for (int ks = 0; ks < 2; ++ks){
      const int kb = ks*32 + lhi*8;
      bf16x8 af[4], bfr[4];
      #pragma unroll
      for (int m = 0; m < 4; ++m) af[m]  = *(const bf16x8*)(As + (wr + m*16 + l15)*64 + kb);
      #pragma unroll
      for (int n = 0; n < 4; ++n) bfr[n] = *(const bf16x8*)(Bs + (wc + n*16 + l15)*64 + kb);
      #pragma unroll
      for (int m = 0; m < 4; ++m)
        #pragma unroll
        for (int n = 0; n < 4; ++n)
          acc[m][n] = __builtin_amdgcn_mfma_f32_16x16x32_bf16(af[m], bfr[n], acc[m][n], 0, 0, 0);
    }
  }

  #pragma unroll
  for (int n = 0; n < 4; ++n){
    const int col = bcol + wc + n*16 + l15;
    const float bv = (MODE == 1) ? bias[col] : 0.f;
    float s = 0.f, s2 = 0.f;
    #pragma unroll
    for (int m = 0; m < 4; ++m){
      #pragma unroll
      for (int r = 0; r < 4; ++r){
        int grow = brow + wr + m*16 + lhi*4 + r;
        float v  = acc[m][n][r] + bv;
        out[(size_t)grow*DF + col] = v;
        if (MODE == 1 && grow < a_valid){ s += v; s2 = fmaf(v, v, s2); }
      }
    }
    if (MODE == 1){
      s  += __shfl_xor(s, 16);  s  += __shfl_xor(s, 32);
      s2 += __shfl_xor(s2, 16); s2 += __shfl_xor(s2, 32);
      if (lhi == 0){ atomicAdd(&msum[col], s); atomicAdd(&ssum[col], s2); }
    }
  }
}

// ---------------- split-K reduce + bias -> bf16 (chunk-local) ----------------
template<int NP>
__global__ __launch_bounds__(256) void k_reduceN(const float* __restrict__ P, size_t zst,
    const float* __restrict__ bias, ushort* __restrict__ xb, int c_off, int nelem){
  int i4 = (blockIdx.x*256 + threadIdx.x)*4;
  if (i4 >= nelem) return;
  int col = i4 & (DF-1);
  f32x4 s = *(const f32x4*)(P + i4);
  #pragma unroll
  for (int p = 1; p < NP; ++p)
    s += *(const f32x4*)(P + (size_t)p*zst + i4);
  f32x4 bv = *(const f32x4*)(bias + col);
  u16x4 o;
  #pragma unroll
  for (int j = 0; j < 4; ++j) o[j] = f2bf(s[j] + bv[j]);
  *(u16x4*)(xb + (size_t)c_off*DF + i4) = o;
}

// ---------------- BN apply (inline scale/shift recompute) + ReLU ----------------
template<bool OB>
__global__ __launch_bounds__(256) void k_bn_apply(const float* __restrict__ y,
    const float* __restrict__ msum, const float* __restrict__ ssum,
    const float* __restrict__ g, const float* __restrict__ bt,
    float inv_n, float* __restrict__ of, ushort* __restrict__ ob){
  size_t i = ((size_t)blockIdx.x*256 + threadIdx.x)*4;
  int col = (int)(i & (DF-1));
  f32x4 v   = *(const f32x4*)(y + i);
  f32x4 mu_ = *(const f32x4*)(msum + col);
  f32x4 s2_ = *(const f32x4*)(ssum + col);
  f32x4 g_  = *(const f32x4*)(g + col);
  f32x4 b_  = *(const f32x4*)(bt + col);
  u16x4 ob_; f32x4 of_;
  #pragma unroll
  for (int j = 0; j < 4; ++j){
    float mu  = mu_[j]*inv_n;
    float var = s2_[j]*inv_n - mu*mu;
    float sc  = g_[j]*rsqrtf(var + EPSBN);
    float val = fmaxf(0.f, fmaf(v[j] - mu, sc, b_[j]));
    if (OB) ob_[j] = f2bf(val); else of_[j] = val;
  }
  if (OB) *(u16x4*)(ob + i) = ob_;
  else    *(f32x4*)(of + i) = of_;
}

// ---------------- launch ----------------
extern "C" void kernel_launch(void* const* d_in, const int* in_sizes, int n_in,
                              void* d_out, int out_size, void* d_ws, size_t ws_size,
                              hipStream_t stream){
  const float* h0   = (const float*)d_in[0];
  const float* norm = (const float*)d_in[1];
  const float* V    = (const float*)d_in[2];
  const float* comp = (const float*)d_in[3];
  const float* bias = (const float*)d_in[4];
  const float* W1   = (const float*)d_in[5];
  const float* b1   = (const float*)d_in[6];
  const float* g1   = (const float*)d_in[7];
  const float* bt1  = (const float*)d_in[8];
  const float* W2   = (const float*)d_in[9];
  const float* b2   = (const float*)d_in[10];
  const float* g2   = (const float*)d_in[11];
  const float* bt2  = (const float*)d_in[12];
  const int* src    = (const int*)d_in[13];
  const int* dst    = (const int*)d_in[14];
  const int* et     = (const int*)d_in[15];

  const int N  = in_sizes[0] / DF;     // 20000
  const int E  = in_sizes[13];         // 320000
  const int MT = (N + 127) / 128;      // 157
  const int MP = MT * 128;             // 20096
  const size_t MPDF = (size_t)MP * DF;
  const size_t PST  = (size_t)CRMAX * DF;  // P z-stride (elements)
  float* out = (float*)d_out;

  uint8_t* w = (uint8_t*)d_ws;
  size_t o = 0;
  auto carve = [&](size_t bytes)->void*{
    void* p = w + o;
    o = (o + bytes + 511) & ~(size_t)511;
    return p;
  };
  float*  y      = (float*) carve(MPDF*4);
  float*  P      = (float*) carve(PST*4*SPLITK);
  ushort* xb     = (ushort*)carve(MPDF*2);
  ushort* Vt     = (ushort*)carve((size_t)NLAY*DF*K1*2);
  ushort* W1t    = (ushort*)carve((size_t)NLAY*DF*DF*2);
  ushort* W2t    = (ushort*)carve((size_t)NLAY*DF*DF*2);
  float*  bnacc  = (float*) carve((size_t)NLAY*4*DF*4);  // {ms1,ss1,ms2,ss2} per layer
  int*    counts = (int*)   carve((size_t)N*4);
  int*    cursor = (int*)   carve((size_t)N*4);
  int*    offs   = (int*)   carve((size_t)(N+1)*4);
  int*    srcs   = (int*)   carve((size_t)E*4);
  int*    ets    = (int*)   carve((size_t)E*4);
  float*  nrms   = (float*) carve((size_t)E*4);
  ushort* S      = (ushort*)(w + o);
  size_t srem = (ws_size > o) ? (ws_size - o) : 0;
  long long crl = ((long long)(srem / ((size_t)K1*2))) & ~127LL;
  int CR = (int)((crl > CRMAX) ? CRMAX : crl);
  if (CR > MP) CR = MP;
  if (CR < 128) CR = 128;

  hipMemsetAsync(counts, 0, (size_t)N*4, stream);
  hipMemsetAsync(cursor, 0, (size_t)N*4, stream);
  hipMemsetAsync(bnacc, 0, (size_t)NLAY*4*DF*4, stream);

  // edge sort by dst + metadata gather (layer-invariant)
  k_hist <<<(E+255)/256, 256, 0, stream>>>(dst, counts, E);
  k_scan <<<1, 1024, 0, stream>>>(counts, offs, N);
  k_place<<<(E+255)/256, 256, 0, stream>>>(dst, offs, cursor, src, et, norm,
                                           srcs, ets, nrms, E);

  // reps[0] = h
  hipMemcpyAsync(out, h0, (size_t)N*DF*4, hipMemcpyDeviceToDevice, stream);

  // all weight transposes upfront
  k_transpose_bf16<<<dim3(K1/32, DF/32, NLAY), 256, 0, stream>>>(V,  Vt,  K1);
  k_transpose_bf16<<<dim3(DF/32, DF/32, NLAY), 256, 0, stream>>>(W1, W1t, DF);
  k_transpose_bf16<<<dim3(DF/32, DF/32, NLAY), 256, 0, stream>>>(W2, W2t, DF);

  const int kspl = K1/64/SPLITK;  // 20
  const float inv_n = 1.f / (float)N;
  for (int l = 0; l < NLAY; ++l){
    const float* hl     = out + (size_t)l*N*DF;
    const float* comp_l = comp + (size_t)l*RREL*NBAS;
    const ushort* Vtl   = Vt + (size_t)l*DF*K1;
    float* ms1 = bnacc + (size_t)(l*4 + 0)*DF;
    float* ss1 = bnacc + (size_t)(l*4 + 1)*DF;
    float* ms2 = bnacc + (size_t)(l*4 + 2)*DF;
    float* ss2 = bnacc + (size_t)(l*4 + 3)*DF;

    for (int c0 = 0; c0 < N; c0 += CR){
      int rows = (N - c0 < CR) ? (N - c0) : CR;
      int gm   = (rows + 127) / 128;
      k_edge_agg<<<rows, DF, 0, stream>>>(hl, srcs, ets, nrms, offs, comp_l, S, c0);
      k_gemm<0><<<dim3(gm, 2, SPLITK), 256, 0, stream>>>(S, Vtl, nullptr, P,
                                                         nullptr, nullptr,
                                                         K1, kspl, rows, PST);
      k_reduceN<SPLITK><<<((rows*64) + 255)/256, 256, 0, stream>>>(
          P, PST, bias + (size_t)l*DF, xb, c0, rows*DF);
    }

    // y1 = x @ W1 + b1 (+fused BN1 stats)
    k_gemm<1><<<dim3(MT, 2), 256, 0, stream>>>(xb, W1t + (size_t)l*DF*DF, b1 + (size_t)l*DF,
                                               y, ms1, ss1, DF, 4, N, 0);
    k_bn_apply<true><<<(int)((size_t)N*DF/1024), 256, 0, stream>>>(
        y, ms1, ss1, g1 + (size_t)l*DF, bt1 + (size_t)l*DF, inv_n, nullptr, xb);

    // y2 = x1 @ W2 + b2 (+fused BN2 stats)
    k_gemm<1><<<dim3(MT, 2), 256, 0, stream>>>(xb, W2t + (size_t)l*DF*DF, b2 + (size_t)l*DF,
                                               y, ms2, ss2, DF, 4, N, 0);
    k_bn_apply<false><<<(int)((size_t)N*DF/1024), 256, 0, stream>>>(
        y, ms2, ss2, g2 + (size_t)l*DF, bt2 + (size_t)l*DF, inv_n,
        out + (size_t)(l+1)*N*DF, nullptr);
  }
}